// Round 10
// baseline (62.944 us; speedup 1.0000x reference)
//
#include <hip/hip_runtime.h>

// Problem constants: x (8, 8192, 512) f32, W (512,128) f32, perm (128,) f32
#define B_ 8
#define N_ 8192
#define D_ 512
#define R_ 128
#define CHUNKS_ 64             // chunks per batch; grid = B_*CHUNKS_ = 512
#define ROWS_ 128              // N_/CHUNKS_

typedef float f4_t __attribute__((ext_vector_type(4)));

// Fused kernel, R8 mechanism (relaxed agent-scope atomics, no wbl2/inv) with
// single-reducer phase 2: the LAST block of each batch (ticket==CHUNKS_-1)
// reduces partial_y -> y[b] (128 floats) and sets flag[b]; all other blocks
// spin on the 4-byte flag and then read only 512 B of y. This removes R8's
// 16 MB of redundant uncached phase-2 traffic.
// 512 blocks x 512 thr = 2 blocks/CU, 16/32 waves: all blocks co-resident,
// so per-b spin is deadlock-free.
__global__ __launch_bounds__(512) void k_fused(const float* __restrict__ x,
                                               const float* __restrict__ W,
                                               const float* __restrict__ perm,
                                               float* __restrict__ partial_y,
                                               float* __restrict__ yglob,
                                               unsigned int* __restrict__ counter,
                                               unsigned int* __restrict__ flag,
                                               float* __restrict__ out) {
    const int b  = blockIdx.x >> 6;         // / CHUNKS_
    const int ck = blockIdx.x & (CHUNKS_ - 1);
    const int t  = threadIdx.x;

    __shared__ float4 s4[512];
    __shared__ float  xs[D_];
    __shared__ float  red[512];
    __shared__ float  yv[R_];
    __shared__ unsigned int sticket;

    // ---- Phase 1: stream ROWS_ rows of x, column-sum into xs ----
    const int dq = t & 127;                 // float4 column over d
    const int rp = t >> 7;                  // 0..3 row-parallel groups
    const float4* x4 = reinterpret_cast<const float4*>(x)
                       + ((size_t)b * N_ + (size_t)ck * ROWS_) * (D_ / 4);

    float4 acc = make_float4(0.f, 0.f, 0.f, 0.f);
    #pragma unroll 8
    for (int n = rp; n < ROWS_; n += 4) {
        float4 v = x4[(size_t)n * (D_ / 4) + dq];
        acc.x += v.x; acc.y += v.y; acc.z += v.z; acc.w += v.w;
    }
    s4[t] = acc;
    __syncthreads();
    if (rp == 0) {
        float4 a1 = s4[dq + 128], a2 = s4[dq + 256], a3 = s4[dq + 384];
        float4 r;
        r.x = (acc.x + a1.x) + (a2.x + a3.x);
        r.y = (acc.y + a1.y) + (a2.y + a3.y);
        r.z = (acc.z + a1.z) + (a2.z + a3.z);
        r.w = (acc.w + a1.w) + (a2.w + a3.w);
        reinterpret_cast<float4*>(xs)[dq] = r;
    }
    __syncthreads();

    // ---- project chunk sum through W: 4 groups x 128 channels ----
    const int r = t & 127;
    const int g = t >> 7;                   // 0..3
    float a = 0.f;
    #pragma unroll 8
    for (int d0 = 0; d0 < 128; ++d0) {
        const int d = g * 128 + d0;
        a = fmaf(xs[d], W[(size_t)d * R_ + r], a);
    }
    red[t] = a;
    __syncthreads();
    if (g == 0) {
        float v = (red[r] + red[r + 128]) + (red[r + 256] + red[r + 384]);
        __hip_atomic_store(&partial_y[(size_t)blockIdx.x * R_ + r], v,
                           __ATOMIC_RELAXED, __HIP_MEMORY_SCOPE_AGENT);
    }
    __syncthreads();                        // vmcnt(0) drain: stores LLC-visible

    // ---- ticket: last block of batch b becomes the reducer ----
    if (t == 0)
        sticket = __hip_atomic_fetch_add(&counter[b], 1u, __ATOMIC_RELAXED,
                                         __HIP_MEMORY_SCOPE_AGENT);
    __syncthreads();

    if (sticket == (unsigned)(CHUNKS_ - 1)) {
        // Reducer: sum 64 chunk projections (32 KB uncached, once per batch).
        const int q4 = t >> 7;              // 0..3 over chunk quarters
        float s = 0.f;
        #pragma unroll
        for (int c = 0; c < CHUNKS_ / 4; ++c) {
            const size_t idx = ((size_t)b * CHUNKS_
                                + (size_t)q4 * (CHUNKS_ / 4) + c) * R_ + r;
            s += __hip_atomic_load(&partial_y[idx], __ATOMIC_RELAXED,
                                   __HIP_MEMORY_SCOPE_AGENT);
        }
        red[t] = s;
        __syncthreads();
        if (g == 0) {
            float yval = ((red[r] + red[r + 128]) + (red[r + 256] + red[r + 384]))
                         * perm[r] * (1.0f / (float)N_);
            __hip_atomic_store(&yglob[b * R_ + r], yval,
                               __ATOMIC_RELAXED, __HIP_MEMORY_SCOPE_AGENT);
        }
        __syncthreads();                    // drain y stores before flag
        if (t == 0)
            __hip_atomic_store(&flag[b], 1u, __ATOMIC_RELAXED,
                               __HIP_MEMORY_SCOPE_AGENT);
    }

    // ---- wait for y[b] (4-byte relaxed poll) ----
    if (t == 0) {
        while (__hip_atomic_load(&flag[b], __ATOMIC_RELAXED,
                                 __HIP_MEMORY_SCOPE_AGENT) == 0u) {
            __builtin_amdgcn_s_sleep(8);
        }
    }
    __syncthreads();

    if (t < R_)
        yv[t] = __hip_atomic_load(&yglob[b * R_ + t], __ATOMIC_RELAXED,
                                  __HIP_MEMORY_SCOPE_AGENT);
    __syncthreads();

    // ---- broadcast-write this block's own ROWS_ output rows ----
    const int q   = t & 31;                 // float4 column 0..31
    const int rp2 = t >> 5;                 // 0..15
    const float4 val4 = reinterpret_cast<const float4*>(yv)[q];
    f4_t val; val.x = val4.x; val.y = val4.y; val.z = val4.z; val.w = val4.w;
    f4_t* out4 = reinterpret_cast<f4_t*>(out)
                 + ((size_t)b * N_ + (size_t)ck * ROWS_) * (R_ / 4);
    #pragma unroll
    for (int n = rp2; n < ROWS_; n += 16)
        out4[(size_t)n * (R_ / 4) + q] = val;
}

extern "C" void kernel_launch(void* const* d_in, const int* in_sizes, int n_in,
                              void* d_out, int out_size, void* d_ws, size_t ws_size,
                              hipStream_t stream) {
    const float* x    = (const float*)d_in[0];
    const float* W    = (const float*)d_in[1];
    const float* perm = (const float*)d_in[2];
    float* out = (float*)d_out;

    unsigned int* counter = (unsigned int*)d_ws;            // 8 x 4 B
    unsigned int* flag    = (unsigned int*)d_ws + B_;       // 8 x 4 B
    float* yglob     = (float*)((char*)d_ws + 256);         // 4 KB
    float* partial_y = (float*)((char*)d_ws + 8192);        // 256 KB

    hipMemsetAsync(d_ws, 0, 2 * B_ * sizeof(unsigned int), stream);
    k_fused<<<dim3(B_ * CHUNKS_), dim3(512), 0, stream>>>(x, W, perm, partial_y,
                                                          yglob, counter, flag, out);
}

// Round 11
// 41.969 us; speedup vs baseline: 1.4998x; 1.4998x over previous
//
#include <hip/hip_runtime.h>

// Problem constants: x (8, 8192, 512) f32, W (512,128) f32, perm (128,) f32
#define B_ 8
#define N_ 8192
#define D_ 512
#define R_ 128
#define CHUNKS_ 128            // chunks per batch; k1 grid = B_*CHUNKS_ = 1024
#define ROWS_ 64               // N_/CHUNKS_

// Kernel 1: per-chunk column-sum of x, then project through W in-block.
// 1024 blocks x 256 threads = 4 blocks/CU (16 waves/CU): same occupancy as
// R3's 512x512 but half the work per block -> shorter straggler tail before
// k2 can launch.
__global__ __launch_bounds__(256) void k_reduce_proj(const float* __restrict__ x,
                                                     const float* __restrict__ W,
                                                     float* __restrict__ partial_y) {
    const int b     = blockIdx.x >> 7;          // / CHUNKS_
    const int chunk = blockIdx.x & (CHUNKS_ - 1);
    const int t  = threadIdx.x;
    const int dq = t & 127;                     // float4 column over d
    const int rp = t >> 7;                      // 0..1 row-parallel groups

    const float4* x4 = reinterpret_cast<const float4*>(x)
                       + ((size_t)b * N_ + (size_t)chunk * ROWS_) * (D_ / 4);

    float4 acc = make_float4(0.f, 0.f, 0.f, 0.f);
    #pragma unroll 8
    for (int n = rp; n < ROWS_; n += 2) {
        float4 v = x4[(size_t)n * (D_ / 4) + dq];
        acc.x += v.x; acc.y += v.y; acc.z += v.z; acc.w += v.w;
    }

    __shared__ float4 s4[256];
    __shared__ float  xs[D_];
    __shared__ float  red[256];

    s4[t] = acc;
    __syncthreads();
    if (rp == 0) {
        float4 a1 = s4[dq + 128];
        float4 r;
        r.x = acc.x + a1.x; r.y = acc.y + a1.y;
        r.z = acc.z + a1.z; r.w = acc.w + a1.w;
        reinterpret_cast<float4*>(xs)[dq] = r;
    }
    __syncthreads();

    // Project: 2 groups x 128 channels; group g covers d = g*256 .. +255.
    const int r = t & 127;
    const int g = t >> 7;                       // 0..1
    float a = 0.f;
    #pragma unroll 8
    for (int d0 = 0; d0 < D_ / 2; ++d0) {
        const int d = g * (D_ / 2) + d0;
        a = fmaf(xs[d], W[(size_t)d * R_ + r], a);
    }
    red[t] = a;
    __syncthreads();
    if (g == 0)
        partial_y[(size_t)blockIdx.x * R_ + r] = red[r] + red[r + 128];
}

// Kernel 2: sum the chunk projections (L2-resident, 64 KB per b), scale by
// perm/N, broadcast-write 64 output rows per block.
// grid = B_*(N_/64) = 1024 blocks x 256 threads (R3-proven geometry).
__global__ __launch_bounds__(256) void k_sumbcast(const float* __restrict__ partial_y,
                                                  const float* __restrict__ perm,
                                                  float* __restrict__ out) {
    const int b  = blockIdx.x >> 7;             // / 128 row-blocks
    const int rb = blockIdx.x & 127;
    const int t  = threadIdx.x;
    const int r    = t & 127;
    const int half = t >> 7;                    // 0..1 over chunk halves

    __shared__ float red[256];
    __shared__ float yv[R_];

    const float* p = partial_y
                     + ((size_t)b * CHUNKS_ + (size_t)half * (CHUNKS_ / 2)) * R_ + r;
    float s = 0.f;
    #pragma unroll 8
    for (int c = 0; c < CHUNKS_ / 2; ++c)
        s += p[(size_t)c * R_];
    red[t] = s;
    __syncthreads();
    if (half == 0)
        yv[r] = (red[r] + red[r + 128]) * perm[r] * (1.0f / (float)N_);
    __syncthreads();

    const int q  = t & 31;                      // float4 column 0..31
    const int rp = t >> 5;                      // 0..7
    const float4 val = reinterpret_cast<const float4*>(yv)[q];
    float4* out4 = reinterpret_cast<float4*>(out)
                   + ((size_t)b * N_ + (size_t)rb * 64) * (R_ / 4);
    #pragma unroll
    for (int n = rp; n < 64; n += 8)
        out4[(size_t)n * (R_ / 4) + q] = val;
}

extern "C" void kernel_launch(void* const* d_in, const int* in_sizes, int n_in,
                              void* d_out, int out_size, void* d_ws, size_t ws_size,
                              hipStream_t stream) {
    const float* x    = (const float*)d_in[0];
    const float* W    = (const float*)d_in[1];
    const float* perm = (const float*)d_in[2];
    float* out = (float*)d_out;
    float* partial_y = (float*)d_ws;            // 1024*128*4 = 512 KB

    k_reduce_proj<<<dim3(B_ * CHUNKS_), dim3(256), 0, stream>>>(x, W, partial_y);
    k_sumbcast  <<<dim3(B_ * (N_ / 64)), dim3(256), 0, stream>>>(partial_y, perm, out);
}